// Round 1
// baseline (276.818 us; speedup 1.0000x reference)
//
#include <hip/hip_runtime.h>
#include <cstdint>
#include <cstddef>

// Problem constants (from reference): B=16, S=4096, C=512, A=0.5
#define PB 16
#define PS 4096
#define PC 512

// ---------------------------------------------------------------------------
// K0: zero the accumulators that later kernels atomicAdd into.
// (d_ws is re-poisoned to 0xAA before every timed launch.)
// ---------------------------------------------------------------------------
__global__ __launch_bounds__(256) void k0_init(int* __restrict__ nCnt,
                                               float* __restrict__ colsum,
                                               float* __restrict__ Lsum,
                                               float* __restrict__ acc) {
    int i = blockIdx.x * 256 + threadIdx.x;
    if (i < PB * PC) { nCnt[i] = 0; colsum[i] = 0.0f; }
    if (i < PB) Lsum[i] = 0.0f;
    if (i < 2) acc[i] = 0.0f;
}

// ---------------------------------------------------------------------------
// K1: one wave per row (b,s). Computes:
//   am[b,s]   = argmax_c predicted[b,s,c]   (first-max tie-break)
//   lse[b,s]  = logsumexp_c predicted[b,s,:]
//   nCnt[b,t] += 1 for t = target[b,s]      (histogram)
//   colsum[b,c] += predicted[b,s,c]         (block-local LDS, then atomics)
//   Lsum[b]   += lse[b,s]
// Block = 256 threads = 4 waves; each block covers 128 consecutive rows of
// one batch b (CH=32 chunks per b -> grid 512 blocks, 2 blocks/CU).
// ---------------------------------------------------------------------------
__global__ __launch_bounds__(256) void k1_rows(const float* __restrict__ pred,
                                               const int* __restrict__ target,
                                               int* __restrict__ am,
                                               float* __restrict__ lse,
                                               int* __restrict__ nCnt,
                                               float* __restrict__ colsum,
                                               float* __restrict__ Lsum) {
    const int CH = 32;            // chunks per batch
    const int RPB = PS / CH;      // 128 rows per block
    int b = blockIdx.x / CH;
    int chunk = blockIdx.x % CH;
    int w = threadIdx.x >> 6;     // wave id in block (0..3)
    int l = threadIdx.x & 63;     // lane

    float cs0 = 0.f, cs1 = 0.f, cs2 = 0.f, cs3 = 0.f;
    float cs4 = 0.f, cs5 = 0.f, cs6 = 0.f, cs7 = 0.f;
    float lseAcc = 0.f;

    __shared__ float lds[4][PC];

    for (int i = 0; i < RPB / 4; ++i) {
        int row = chunk * RPB + i * 4 + w;
        size_t base = ((size_t)(b * PS + row)) * PC;
        const float4* p = (const float4*)(pred + base);
        float4 v0 = p[l];
        float4 v1 = p[64 + l];

        // lane-local argmax over 8 elements, earliest-column preference
        float bv = v0.x; int bi = 4 * l;
        if (v0.y > bv) { bv = v0.y; bi = 4 * l + 1; }
        if (v0.z > bv) { bv = v0.z; bi = 4 * l + 2; }
        if (v0.w > bv) { bv = v0.w; bi = 4 * l + 3; }
        if (v1.x > bv) { bv = v1.x; bi = 256 + 4 * l; }
        if (v1.y > bv) { bv = v1.y; bi = 256 + 4 * l + 1; }
        if (v1.z > bv) { bv = v1.z; bi = 256 + 4 * l + 2; }
        if (v1.w > bv) { bv = v1.w; bi = 256 + 4 * l + 3; }

        // wave butterfly: (max value, min index on tie) is associative+commutative
        #pragma unroll
        for (int off = 1; off < 64; off <<= 1) {
            float ov = __shfl_xor(bv, off, 64);
            int   oi = __shfl_xor(bi, off, 64);
            if (ov > bv || (ov == bv && oi < bi)) { bv = ov; bi = oi; }
        }
        // bv is now the row max; bi the first argmax index.

        float se = expf(v0.x - bv) + expf(v0.y - bv) + expf(v0.z - bv) + expf(v0.w - bv)
                 + expf(v1.x - bv) + expf(v1.y - bv) + expf(v1.z - bv) + expf(v1.w - bv);
        #pragma unroll
        for (int off = 1; off < 64; off <<= 1) se += __shfl_xor(se, off, 64);
        float l_row = bv + logf(se);

        if (l == 0) {
            int gidx = b * PS + row;
            lse[gidx] = l_row;
            am[gidx] = bi;
            int t = target[gidx];
            atomicAdd(&nCnt[b * PC + t], 1);
            lseAcc += l_row;
        }

        cs0 += v0.x; cs1 += v0.y; cs2 += v0.z; cs3 += v0.w;
        cs4 += v1.x; cs5 += v1.y; cs6 += v1.z; cs7 += v1.w;
    }

    if (l == 0) atomicAdd(&Lsum[b], lseAcc);

    // column sums: each wave owns its LDS slice (no intra-wave column overlap)
    lds[w][4 * l + 0] = cs0; lds[w][4 * l + 1] = cs1;
    lds[w][4 * l + 2] = cs2; lds[w][4 * l + 3] = cs3;
    lds[w][256 + 4 * l + 0] = cs4; lds[w][256 + 4 * l + 1] = cs5;
    lds[w][256 + 4 * l + 2] = cs6; lds[w][256 + 4 * l + 3] = cs7;
    __syncthreads();
    for (int c = threadIdx.x; c < PC; c += 256) {
        float s = lds[0][c] + lds[1][c] + lds[2][c] + lds[3][c];
        atomicAdd(&colsum[b * PC + c], s);
    }
}

// ---------------------------------------------------------------------------
// K2: per-batch exclusive prefix sum of nCnt -> bucket offsets (global index),
// plus a scatter cursor copy. One block (512 threads) per batch.
// ---------------------------------------------------------------------------
__global__ __launch_bounds__(512) void k2_scan(const int* __restrict__ nCnt,
                                               int* __restrict__ offs,
                                               int* __restrict__ cursor) {
    int b = blockIdx.x;
    int t = threadIdx.x;
    __shared__ int sc[PC];
    int x = nCnt[b * PC + t];
    sc[t] = x;
    __syncthreads();
    for (int off = 1; off < PC; off <<= 1) {
        int v = (t >= off) ? sc[t - off] : 0;
        __syncthreads();
        sc[t] += v;
        __syncthreads();
    }
    int g = b * PS + (sc[t] - x);   // global exclusive offset
    offs[b * PC + t] = g;
    cursor[b * PC + t] = g;
}

// ---------------------------------------------------------------------------
// K3: counting-sort scatter of positions s into per-(b,target) buckets.
// ---------------------------------------------------------------------------
__global__ __launch_bounds__(256) void k3_scatter(const int* __restrict__ target,
                                                  int* __restrict__ cursor,
                                                  int* __restrict__ bucket) {
    int gid = blockIdx.x * 256 + threadIdx.x;   // < B*S
    int b = gid >> 12;
    int s = gid & (PS - 1);
    int t = target[gid];
    int pos = atomicAdd(&cursor[b * PC + t], 1);
    bucket[pos] = s;
}

// ---------------------------------------------------------------------------
// K4: one thread per (b,t) pair. Computes the mode m of am[] over the bucket
// (tie -> smallest class index, matching argmax-first), then
//   eq_sum  = sum_{s in bucket} (lse[b,s] - pred[b,s,m])
//   ne_sum  = (Lsum[b] - colsum[b,m]) - eq_sum
//   val, keep per reference; wave-reduced into acc[0]=sum(val), acc[1]=count.
// ---------------------------------------------------------------------------
__global__ __launch_bounds__(256) void k4_pairs(const float* __restrict__ pred,
                                                const int* __restrict__ nCnt,
                                                const int* __restrict__ offs,
                                                const int* __restrict__ bucket,
                                                const int* __restrict__ am,
                                                const float* __restrict__ lse,
                                                const float* __restrict__ colsum,
                                                const float* __restrict__ Lsum,
                                                float* __restrict__ acc) {
    __shared__ int cache[256][33];   // +1 pad: stride 33 -> conflict-free
    int pair = blockIdx.x * 256 + threadIdx.x;  // < B*C
    int b = pair >> 9;
    int k = nCnt[pair];
    int start = offs[pair];

    float val = 0.f;
    int keep = 0;

    if (k > 0) {
        float lseSum = 0.f;
        for (int i = 0; i < k; ++i) {
            int s = bucket[start + i];
            int a = am[(b << 12) + s];
            if (i < 32) cache[threadIdx.x][i] = a;
            lseSum += lse[(b << 12) + s];
        }
        // mode with tie -> smallest value
        int bc = 0, bvv = 0;
        if (k <= 32) {
            for (int i = 0; i < k; ++i) {
                int v = cache[threadIdx.x][i];
                int c = 0;
                for (int j = 0; j < k; ++j) c += (cache[threadIdx.x][j] == v) ? 1 : 0;
                if (c > bc || (c == bc && v < bvv)) { bc = c; bvv = v; }
            }
        } else {
            // rare fallback (bucket larger than cache): recompute from memory
            for (int i = 0; i < k; ++i) {
                int v = am[(b << 12) + bucket[start + i]];
                int c = 0;
                for (int j = 0; j < k; ++j)
                    c += (am[(b << 12) + bucket[start + j]] == v) ? 1 : 0;
                if (c > bc || (c == bc && v < bvv)) { bc = c; bvv = v; }
            }
        }
        int m = bvv;

        float ep = 0.f;
        for (int i = 0; i < k; ++i) {
            int s = bucket[start + i];
            ep += pred[(((size_t)(b << 12)) + s) * PC + m];
        }
        float eq_sum = lseSum - ep;
        float total_term = Lsum[b] - colsum[(b << 9) + m];
        float ne_sum = total_term - eq_sum;
        float nf = (float)k;
        float eq_loss = eq_sum / fmaxf(nf, 1.0f);
        float ne_mean = ne_sum / fmaxf((float)PS - nf, 1.0f);
        // present == true here (k > 0)
        float ne_loss = 1.0f / ((ne_mean != 0.0f) ? ne_mean : 1.0f);
        val = 0.5f * eq_loss + 0.5f * ne_loss;
        keep = (val != 0.0f) ? 1 : 0;
    }
    // pairs with k==0 contribute nothing (present=false -> keep=false), matching ref.

    float vs = keep ? val : 0.0f;
    float ks = (float)keep;
    #pragma unroll
    for (int off = 1; off < 64; off <<= 1) {
        vs += __shfl_xor(vs, off, 64);
        ks += __shfl_xor(ks, off, 64);
    }
    if ((threadIdx.x & 63) == 0) {
        atomicAdd(&acc[0], vs);
        atomicAdd(&acc[1], ks);
    }
}

// ---------------------------------------------------------------------------
// K5: final scalar.
// ---------------------------------------------------------------------------
__global__ void k5_final(const float* __restrict__ acc, float* __restrict__ out) {
    if (threadIdx.x == 0 && blockIdx.x == 0)
        out[0] = acc[0] / fmaxf(acc[1], 1.0f);
}

extern "C" void kernel_launch(void* const* d_in, const int* in_sizes, int n_in,
                              void* d_out, int out_size, void* d_ws, size_t ws_size,
                              hipStream_t stream) {
    const float* pred = (const float*)d_in[0];   // (B,S,C) f32
    const int* target = (const int*)d_in[1];     // (B,S) int
    float* out = (float*)d_out;

    char* w = (char*)d_ws;
    int*   am     = (int*)(w + 0);          // B*S ints   = 256 KiB
    float* lse    = (float*)(w + 262144);   // B*S floats = 256 KiB
    int*   bucket = (int*)(w + 524288);     // B*S ints   = 256 KiB
    int*   nCnt   = (int*)(w + 786432);     // B*C ints   =  32 KiB
    int*   offs   = (int*)(w + 819200);     // B*C ints
    int*   cursor = (int*)(w + 851968);     // B*C ints
    float* colsum = (float*)(w + 884736);   // B*C floats
    float* Lsum   = (float*)(w + 917504);   // B floats
    float* acc    = (float*)(w + 917568);   // 2 floats

    k0_init<<<32, 256, 0, stream>>>(nCnt, colsum, Lsum, acc);
    k1_rows<<<PB * 32, 256, 0, stream>>>(pred, target, am, lse, nCnt, colsum, Lsum);
    k2_scan<<<PB, 512, 0, stream>>>(nCnt, offs, cursor);
    k3_scatter<<<(PB * PS) / 256, 256, 0, stream>>>(target, cursor, bucket);
    k4_pairs<<<(PB * PC) / 256, 256, 0, stream>>>(pred, nCnt, offs, bucket, am, lse,
                                                  colsum, Lsum, acc);
    k5_final<<<1, 64, 0, stream>>>(acc, out);
}